// Round 4
// baseline (173.844 us; speedup 1.0000x reference)
//
#include <hip/hip_runtime.h>
#include <math.h>

#define N_PTS 65536
#define M_IND 1024
#define KNN 16
#define JITTER 1e-4f

// Packed lower-triangular Su: P[i*(i+1)/2 + j], j <= i.
#define PACKED_FLOATS (M_IND * (M_IND + 1) / 2)               // 524800
#define PACKED_BYTES  ((size_t)PACKED_FLOATS * sizeof(float)) // 2,099,200 B
#define QBG_BYTES     ((size_t)N_PTS * KNN * 8)               // 8,388,608 B

#define TSU 32
#define SU_BLOCKS 528          // 32*33/2 triangular tiles
#define PTS_PER_BLK 128        // fused-fallback shape (512 blocks)
#define QSTRIDE 17             // u64 per point row (136 B)
#define GRID_BLKS (N_PTS / PTS_PER_BLK)   // 512

// R14: SPLIT-KERNEL path (preferred when ws fits P+qbg):
//   sel_kernel: 1024 blk x 256 thr, 1 pt/thread (R11-validated selection),
//     su tiles on blocks <528, keys -> global qbg. Kernel boundary replaces
//     the ctr spin => NO co-residency requirement, any grid is safe.
//   p2_kernel: 1024 blk x 128 thr, 2 threads/point => 8 waves/CU (2x today's
//     phase-2 residency); qs scattered-P rows split by parity across the pair.
// Register-regime ledger (R11/R12): phase-2 live set needs the 2-waves/SIMD
// 512-unified budget; both new kernels keep cap>=256 (launch_bounds *,2).
// Fused mode 2/1/0 kept verbatim as fallback.

// ---------------------------------------------------------------------------
// One 32x32 Su tile (packed tril(Lu Lu^T)). As/Bs are LDS scratch.
// ---------------------------------------------------------------------------
__device__ __forceinline__ void su_tile(const float* __restrict__ Lu_raw,
                                        float* __restrict__ P,
                                        int bid, int tid,
                                        float (*As)[36], float (*Bs)[36]) {
    int rt = (int)((sqrtf(8.0f * (float)bid + 1.0f) - 1.0f) * 0.5f);
    while ((rt + 1) * (rt + 2) / 2 <= bid) ++rt;
    while (rt * (rt + 1) / 2 > bid) --rt;
    int ct = bid - rt * (rt + 1) / 2;   // ct <= rt
    int i0 = rt * TSU, j0 = ct * TSU;

    int tx = tid & 15, ty = tid >> 4;
    int sr = tid >> 3, sc = (tid & 7) << 2;
    float a00 = 0.f, a01 = 0.f, a10 = 0.f, a11 = 0.f;

    int nch = ct + 1;                      // k-chunks of 32 (k <= j0+31)
    int gi = i0 + sr, gj = j0 + sr;
    float4 pa = *(const float4*)(Lu_raw + (unsigned)gi * M_IND + sc);
    float4 pb = *(const float4*)(Lu_raw + (unsigned)gj * M_IND + sc);

    for (int c = 0; c < nch; ++c) {
        int gk = (c << 5) + sc;
        float aa[4] = {pa.x, pa.y, pa.z, pa.w};
        float bb[4] = {pb.x, pb.y, pb.z, pb.w};
        #pragma unroll
        for (int q = 0; q < 4; ++q) {
            int k = gk + q;
            aa[q] = (k < gi) ? aa[q] : ((k == gi) ? __expf(aa[q]) : 0.0f);
            bb[q] = (k < gj) ? bb[q] : ((k == gj) ? __expf(bb[q]) : 0.0f);
        }
        *(float4*)&As[sr][sc] = make_float4(aa[0], aa[1], aa[2], aa[3]);
        *(float4*)&Bs[sr][sc] = make_float4(bb[0], bb[1], bb[2], bb[3]);
        __syncthreads();
        if (c + 1 < nch) {
            int kn = ((c + 1) << 5) + sc;
            pa = *(const float4*)(Lu_raw + (unsigned)gi * M_IND + kn);
            pb = *(const float4*)(Lu_raw + (unsigned)gj * M_IND + kn);
        }
        #pragma unroll
        for (int kk = 0; kk < 32; kk += 4) {
            float4 av0 = *(const float4*)&As[ty][kk];
            float4 av1 = *(const float4*)&As[ty + 16][kk];
            float4 bv0 = *(const float4*)&Bs[tx][kk];
            float4 bv1 = *(const float4*)&Bs[tx + 16][kk];
            a00 = fmaf(av0.x, bv0.x, fmaf(av0.y, bv0.y, fmaf(av0.z, bv0.z, fmaf(av0.w, bv0.w, a00))));
            a01 = fmaf(av0.x, bv1.x, fmaf(av0.y, bv1.y, fmaf(av0.z, bv1.z, fmaf(av0.w, bv1.w, a01))));
            a10 = fmaf(av1.x, bv0.x, fmaf(av1.y, bv0.y, fmaf(av1.z, bv0.z, fmaf(av1.w, bv0.w, a10))));
            a11 = fmaf(av1.x, bv1.x, fmaf(av1.y, bv1.y, fmaf(av1.z, bv1.z, fmaf(av1.w, bv1.w, a11))));
        }
        __syncthreads();
    }

    int ia = i0 + ty, ib = i0 + ty + 16;
    int ja = j0 + tx, jb = j0 + tx + 16;
    if (ja <= ia) P[((unsigned)ia * (ia + 1) >> 1) + ja] = a00;
    if (jb <= ia) P[((unsigned)ia * (ia + 1) >> 1) + jb] = a01;
    if (ja <= ib) P[((unsigned)ib * (ib + 1) >> 1) + ja] = a10;
    if (jb <= ib) P[((unsigned)ib * (ib + 1) >> 1) + jb] = a11;
}

// Standalone su kernel (non-fused fallback path only).
__global__ __launch_bounds__(256) void su_kernel(const float* __restrict__ Lu_raw,
                                                 float* __restrict__ P) {
    __shared__ float As[TSU][36];
    __shared__ float Bs[TSU][36];
    su_tile(Lu_raw, P, blockIdx.x, threadIdx.x, As, Bs);
}

// ---------------------------------------------------------------------------
// Sorting-network helpers.
// ---------------------------------------------------------------------------
__device__ __forceinline__ void ce(unsigned long long& x, unsigned long long& y) {
    unsigned long long a = x, b = y;
    bool c = a < b;
    x = c ? a : b;
    y = c ? b : a;
}
__device__ __forceinline__ void ce(float& x, float& y) {
    float a = fminf(x, y), b = fmaxf(x, y);
    x = a; y = b;
}

template <typename KT>
__device__ __forceinline__ void sort16(KT* a) {
    #pragma unroll
    for (int p = 1; p < 16; p <<= 1)
        #pragma unroll
        for (int k = p; k >= 1; k >>= 1)
            #pragma unroll
            for (int j = k & (p - 1); j + k < 16; j += 2 * k)
                #pragma unroll
                for (int i = 0; i < k; ++i)
                    if (i + j + k < 16)
                        if (((i + j) / (2 * p)) == ((i + j + k) / (2 * p)))
                            ce(a[i + j], a[i + j + k]);
}

template <typename KT>
__device__ __forceinline__ void cleanup16(KT* a) {
    #pragma unroll
    for (int d = 8; d >= 1; d >>= 1)
        #pragma unroll
        for (int i = 0; i < 16; ++i)
            if ((i & d) == 0) ce(a[i], a[i | d]);
}

// u-space distance surrogate: u = 0.5*|z|^2 - x.z  (Zs.w holds 0.5*|z|^2).
// d = max(2u + xq, 0) is monotone in u.
__device__ __forceinline__ float uval(float4 z, float xn0, float xn1, float xn2) {
    return fmaf(xn0, z.x, fmaf(xn1, z.y, fmaf(xn2, z.z, z.w)));
}

// ---------------------------------------------------------------------------
// SPLIT KERNEL A: su tiles (blocks < 528) + selection, 1 pt per thread-quad,
// 64 pts/block, 1024 blocks. Keys written to global qbg. No device sync.
// LDS: Zs 16384 | 9216 shared by {myc staging 8704, su As/Bs 9216} = 25600 B.
// ---------------------------------------------------------------------------
__global__ __launch_bounds__(256, 2) void sel_kernel(const float* __restrict__ X,
                                                     const float* __restrict__ Z,
                                                     float* __restrict__ P,
                                                     const float* __restrict__ Lu_raw,
                                                     unsigned long long* __restrict__ qbg) {
    __shared__ __align__(16) char smem[25600];
    float4* Zs = (float4*)smem;                                   // 16384 B
    unsigned long long* qb = (unsigned long long*)(smem + 16384); // myc staging
    int tid = threadIdx.x;

    for (int r = tid; r < M_IND; r += 256) {
        float zx = Z[r * 3 + 0], zy = Z[r * 3 + 1], zz = Z[r * 3 + 2];
        Zs[r] = make_float4(zx, zy, zz, 0.5f * (zx * zx + zy * zy + zz * zz));
    }

    if (blockIdx.x < SU_BLOCKS) {
        // As/Bs alias the myc region; su_tile's internal barriers also order
        // the Zs staging before pass 1, and its final barrier orders the last
        // As/Bs reads before the myc writes below.
        float (*As)[36] = (float (*)[36])(smem + 16384);
        float (*Bs)[36] = (float (*)[36])(smem + 16384 + 4608);
        su_tile(Lu_raw, P, blockIdx.x, tid, As, Bs);
    } else {
        __syncthreads();
    }

    int pt = tid >> 2, sub = tid & 3;     // pt 0..63, one point per thread-quad
    int n = blockIdx.x * 64 + pt;
    float x0 = X[n * 3 + 0], x1 = X[n * 3 + 1], x2 = X[n * 3 + 2];
    float xq = fmaf(x0, x0, fmaf(x1, x1, x2 * x2));
    float xn0 = -x0, xn1 = -x1, xn2 = -x2;
    int mbase = sub << 8;
    int rot = sub << 1;   // subs land on disjoint bank quads

    // ---- Pass 1: 16 interleaved class minima (u-space) ----
    float T[16];
    #pragma unroll
    for (int j = 0; j < 16; ++j) T[j] = 3.4e38f;
    #pragma unroll 1
    for (int c = 0; c < 16; ++c) {
        int base = mbase + (c << 4);
        #pragma unroll
        for (int j = 0; j < 16; ++j) {
            int m = base + ((j + rot) & 15);
            float4 z = Zs[m];
            T[j] = fminf(T[j], uval(z, xn0, xn1, xn2));
        }
    }
    sort16(T);
    #pragma unroll
    for (int round = 1; round <= 2; round <<= 1) {
        float o[16];
        #pragma unroll
        for (int i = 0; i < 16; ++i) o[i] = __shfl_xor(T[i], round, 64);
        #pragma unroll
        for (int i = 0; i < 16; ++i) T[i] = fminf(T[i], o[15 - i]);
        cleanup16(T);
    }
    float Tstar = T[15];   // u-space threshold

    // ---- Pass 2: collect indices with u <= Tstar (u16, cap 16/sub) ----
    unsigned short* myc = ((unsigned short*)qb) + pt * (QSTRIDE * 4) + sub * 16;
    int cnt = 0;
    #pragma unroll 1
    for (int c = 0; c < 16; ++c) {
        int base = mbase + (c << 4);
        #pragma unroll
        for (int j = 0; j < 16; ++j) {
            int m = base + ((j + rot) & 15);
            float4 z = Zs[m];
            float u = uval(z, xn0, xn1, xn2);
            if (u <= Tstar) { if (cnt < 16) myc[cnt] = (unsigned short)m; ++cnt; }
        }
    }

    int ovf = cnt > 16 ? 1 : 0;
    ovf |= __shfl_xor(ovf, 1, 64);
    ovf |= __shfl_xor(ovf, 2, 64);

    unsigned long long* kout = qbg + (size_t)n * KNN;

    // ---- finalize: d-space keys, sort, quad-merge, write to global ----
    if (!ovf) {
        const unsigned long long* m64 = (const unsigned long long*)myc;
        unsigned long long raw[4] = {m64[0], m64[1], m64[2], m64[3]};
        unsigned long long C[16];
        #pragma unroll
        for (int i = 0; i < 16; ++i) {
            int m = (int)((raw[i >> 2] >> ((i & 3) * 16)) & 0x3FF);
            float u = uval(Zs[m], xn0, xn1, xn2);
            float d = fmaxf(fmaf(2.0f, u, xq), 0.0f);
            unsigned long long key =
                ((unsigned long long)__float_as_uint(d) << 32) | (unsigned)m;
            C[i] = (i < cnt) ? key : ~0ULL;
        }
        sort16(C);
        #pragma unroll
        for (int round = 1; round <= 2; round <<= 1) {
            unsigned long long o[16];
            #pragma unroll
            for (int i = 0; i < 16; ++i) o[i] = __shfl_xor(C[i], round, 64);
            #pragma unroll
            for (int i = 0; i < 16; ++i) {
                unsigned long long b = o[15 - i];
                C[i] = C[i] < b ? C[i] : b;
            }
            cleanup16(C);
        }
        if (sub == 0) {
            #pragma unroll
            for (int i = 0; i < 16; ++i) kout[i] = C[i];
        }
    } else if (sub == 0) {
        // Exact serial fallback (rare): full scan, running top-16.
        unsigned long long R[16];
        #pragma unroll
        for (int i = 0; i < 16; ++i) R[i] = ~0ULL;
        for (int m = 0; m < M_IND; ++m) {
            float u = uval(Zs[m], xn0, xn1, xn2);
            float d = fmaxf(fmaf(2.0f, u, xq), 0.0f);
            unsigned long long kk =
                ((unsigned long long)__float_as_uint(d) << 32) | (unsigned)m;
            if (kk < R[15]) {
                #pragma unroll
                for (int j = 0; j < 16; ++j) {
                    unsigned long long t = R[j];
                    bool cc = kk < t;
                    R[j] = cc ? kk : t;
                    kk = cc ? t : kk;
                }
            }
        }
        #pragma unroll
        for (int i = 0; i < 16; ++i) kout[i] = R[i];
    }
}

// ---------------------------------------------------------------------------
// SPLIT KERNEL B: phase 2, 2 threads per point (role 0/1), 64 pts/block,
// 1024 blocks x 128 thr => 8 waves/CU (2/SIMD). Pair splits the scattered-P
// qs loop by row parity; Cholesky/solves redundant (latency chains).
// LDS: Zs 16384 | mus 4096 | xch 512 = 20992 B.
// ---------------------------------------------------------------------------
__global__ __launch_bounds__(128, 2) void p2_kernel(const float* __restrict__ Z,
                                                    const float* __restrict__ mu,
                                                    const float* __restrict__ P,
                                                    const unsigned long long* __restrict__ qbg,
                                                    float* __restrict__ out) {
    __shared__ __align__(16) char smem[20992];
    float4* Zs = (float4*)smem;                   // 16384 B
    float* mus = (float*)(smem + 16384);          // 4096 B
    float* xch = (float*)(smem + 20480);          // 512 B
    int tid = threadIdx.x;

    for (int r = tid; r < M_IND; r += 128) {
        float zx = Z[r * 3 + 0], zy = Z[r * 3 + 1], zz = Z[r * 3 + 2];
        Zs[r] = make_float4(zx, zy, zz, 0.5f * (zx * zx + zy * zy + zz * zz));
        mus[r] = mu[r];
    }
    __syncthreads();

    int role = tid >> 6;                // wave-uniform
    int pt = tid & 63;
    int n = blockIdx.x * 64 + pt;

    int idx[KNN];
    float kv[KNN];
    float nx[KNN], ny[KNN], nz[KNN], nq[KNN];
    const unsigned long long* kp = qbg + (size_t)n * KNN;
    #pragma unroll
    for (int a = 0; a < KNN; ++a) {
        unsigned long long k = kp[a];
        idx[a] = (int)(k & 0xFFFFFFFFULL);
        float d = __uint_as_float((unsigned)(k >> 32));
        kv[a] = __expf(-0.5f * d);            // lKxz entries
        float4 z = Zs[idx[a]];
        nx[a] = z.x; ny[a] = z.y; nz[a] = z.z; nq[a] = z.w;   // nq = 0.5*|z|^2
    }

    // A = lKzz + JITTER*I (lower tri); diag = 1 + 2*JITTER.
    float A[KNN * (KNN + 1) / 2];
    #pragma unroll
    for (int r = 0; r < KNN; ++r) {
        A[r * (r + 1) / 2 + r] = 1.0f + 2.0f * JITTER;
        #pragma unroll
        for (int c = 0; c < r; ++c) {
            float dot = fmaf(nx[r], nx[c], fmaf(ny[r], ny[c], nz[r] * nz[c]));
            A[r * (r + 1) / 2 + c] = __expf(fminf(dot - nq[r] - nq[c], 0.0f));
        }
    }

    // In-place Cholesky; 1/L[c][c] stored on the diagonal (rsqrt).
    #pragma unroll
    for (int c = 0; c < KNN; ++c) {
        float diag = A[c * (c + 1) / 2 + c];
        #pragma unroll
        for (int k = 0; k < c; ++k) {
            float l = A[c * (c + 1) / 2 + k];
            diag = fmaf(-l, l, diag);
        }
        float rinv = __frsqrt_rn(fmaxf(diag, 1e-12f));
        A[c * (c + 1) / 2 + c] = rinv;
        #pragma unroll
        for (int r = c + 1; r < KNN; ++r) {
            float v = A[r * (r + 1) / 2 + c];
            #pragma unroll
            for (int k = 0; k < c; ++k)
                v = fmaf(-A[r * (r + 1) / 2 + k], A[c * (c + 1) / 2 + k], v);
            A[r * (r + 1) / 2 + c] = v * rinv;
        }
    }

    // Solve A w = kv.
    float w[KNN];
    #pragma unroll
    for (int r = 0; r < KNN; ++r) {
        float v = kv[r];
        #pragma unroll
        for (int c = 0; c < r; ++c) v = fmaf(-A[r * (r + 1) / 2 + c], w[c], v);
        w[r] = v * A[r * (r + 1) / 2 + r];
    }
    #pragma unroll
    for (int r = KNN - 1; r >= 0; --r) {
        float v = w[r];
        #pragma unroll
        for (int c = r + 1; c < KNN; ++c) v = fmaf(-A[c * (c + 1) / 2 + r], w[c], v);
        w[r] = v * A[r * (r + 1) / 2 + r];
    }

    float wk = 0.f, ww = 0.f, mean = 0.f;
    #pragma unroll
    for (int a = 0; a < KNN; ++a) {
        wk = fmaf(w[a], kv[a], wk);
        ww = fmaf(w[a], w[a], ww);
        mean = fmaf(w[a], mus[idx[a]], mean);
    }

    // qs = w^T Su[idx,idx] w — rows split by parity across the pair.
    float qs_p = 0.f;
    #pragma unroll
    for (int r = 0; r < KNN; ++r) {
        if ((r & 1) == role) {
            int a = idx[r];
            float wr = w[r];
            float rowacc = 0.f;
            #pragma unroll
            for (int c = 0; c < r; ++c) {
                int b = idx[c];
                int hi = a > b ? a : b;
                int lo = a > b ? b : a;
                rowacc = fmaf(w[c], P[((unsigned)hi * (hi + 1) >> 1) + lo], rowacc);
            }
            qs_p = fmaf(wr, fmaf(wr, P[((unsigned)a * (a + 1) >> 1) + a], 2.0f * rowacc), qs_p);
        }
    }
    xch[tid] = qs_p;
    __syncthreads();
    if (role == 0) {
        float qs = qs_p + xch[tid + 64];
        float cov = 1.0f - (wk - JITTER * ww) + qs;
        float sd = sqrtf(fmaxf(cov, 0.05f));
        out[n] = mean;
        out[N_PTS + n] = sd;
    }
}

// ---------------------------------------------------------------------------
// FUSED fallback (R13, unchanged): MODE 2 in-kernel su + device-flag sync;
// MODE 1 two-kernel; MODE 0 no-workspace exact fallback.
// ---------------------------------------------------------------------------
template <int MODE>
__global__ __launch_bounds__(256, 2) void vnngp_kernel(const float* __restrict__ X,
                                                       const float* __restrict__ Z,
                                                       const float* __restrict__ mu,
                                                       float* __restrict__ P,
                                                       const float* __restrict__ Lu_raw,
                                                       unsigned int* __restrict__ ctr,
                                                       float* __restrict__ out) {
    __shared__ __align__(16) char smem[37888];
    float4* Zs = (float4*)smem;                                  // 16 KB
    float* mus = (float*)(smem + 16384);                         // 4 KB
    unsigned long long* qb = (unsigned long long*)(smem + 20480); // 17 KB
    int tid = threadIdx.x;

    for (int r = tid; r < M_IND; r += 256) {
        float zx = Z[r * 3 + 0], zy = Z[r * 3 + 1], zz = Z[r * 3 + 2];
        Zs[r] = make_float4(zx, zy, zz, 0.5f * (zx * zx + zy * zy + zz * zz));
        mus[r] = mu[r];
    }

    if (MODE == 2) {
        float (*As)[36] = (float (*)[36])(smem + 20480);
        float (*Bs)[36] = (float (*)[36])(smem + 20480 + 4608);
        int t = blockIdx.x;
        #pragma unroll
        for (int r = 16; r < 32; ++r) {
            int s = (r * (r + 1)) >> 1;
            if (t >= s) ++t;
        }
        su_tile(Lu_raw, P, t, tid, As, Bs);       // contains __syncthreads
        if (blockIdx.x < 16) {
            int r = 16 + blockIdx.x;
            su_tile(Lu_raw, P, (r * (r + 1)) >> 1, tid, As, Bs);
        }
        __syncthreads();
        if (tid == 0) {
            __threadfence();
            atomicAdd(ctr, 1u);
        }
    } else {
        __syncthreads();
    }

    {
        int pt = tid >> 2, sub = tid & 3;
        int nA = blockIdx.x * PTS_PER_BLK + pt;
        int nB = nA + 64;
        float xA0 = X[nA * 3 + 0], xA1 = X[nA * 3 + 1], xA2 = X[nA * 3 + 2];
        float xB0 = X[nB * 3 + 0], xB1 = X[nB * 3 + 1], xB2 = X[nB * 3 + 2];
        float xqA = fmaf(xA0, xA0, fmaf(xA1, xA1, xA2 * xA2));
        float xqB = fmaf(xB0, xB0, fmaf(xB1, xB1, xB2 * xB2));
        float nA0 = -xA0, nA1 = -xA1, nA2 = -xA2;
        float nB0 = -xB0, nB1 = -xB1, nB2 = -xB2;
        int mbase = sub << 8;
        int rot = sub << 1;

        float TA[16], TB[16];
        #pragma unroll
        for (int j = 0; j < 16; ++j) { TA[j] = 3.4e38f; TB[j] = 3.4e38f; }
        #pragma unroll 1
        for (int c = 0; c < 16; ++c) {
            int base = mbase + (c << 4);
            #pragma unroll
            for (int j = 0; j < 16; ++j) {
                int m = base + ((j + rot) & 15);
                float4 z = Zs[m];
                TA[j] = fminf(TA[j], uval(z, nA0, nA1, nA2));
                TB[j] = fminf(TB[j], uval(z, nB0, nB1, nB2));
            }
        }
        sort16(TA);
        sort16(TB);
        #pragma unroll
        for (int round = 1; round <= 2; round <<= 1) {
            float oA[16], oB[16];
            #pragma unroll
            for (int i = 0; i < 16; ++i) {
                oA[i] = __shfl_xor(TA[i], round, 64);
                oB[i] = __shfl_xor(TB[i], round, 64);
            }
            #pragma unroll
            for (int i = 0; i < 16; ++i) {
                TA[i] = fminf(TA[i], oA[15 - i]);
                TB[i] = fminf(TB[i], oB[15 - i]);
            }
            cleanup16(TA);
            cleanup16(TB);
        }
        float TstarA = TA[15], TstarB = TB[15];

        unsigned short* mycA = ((unsigned short*)qb) + pt * (QSTRIDE * 4) + sub * 16;
        unsigned short* mycB = ((unsigned short*)qb) + (pt + 64) * (QSTRIDE * 4) + sub * 16;
        int cntA = 0, cntB = 0;
        #pragma unroll 1
        for (int c = 0; c < 16; ++c) {
            int base = mbase + (c << 4);
            #pragma unroll
            for (int j = 0; j < 16; ++j) {
                int m = base + ((j + rot) & 15);
                float4 z = Zs[m];
                float uA = uval(z, nA0, nA1, nA2);
                float uB = uval(z, nB0, nB1, nB2);
                if (uA <= TstarA) { if (cntA < 16) mycA[cntA] = (unsigned short)m; ++cntA; }
                if (uB <= TstarB) { if (cntB < 16) mycB[cntB] = (unsigned short)m; ++cntB; }
            }
        }

        int ovfA = cntA > 16 ? 1 : 0;
        ovfA |= __shfl_xor(ovfA, 1, 64);
        ovfA |= __shfl_xor(ovfA, 2, 64);
        int ovfB = cntB > 16 ? 1 : 0;
        ovfB |= __shfl_xor(ovfB, 1, 64);
        ovfB |= __shfl_xor(ovfB, 2, 64);

        if (!ovfA) {
            const unsigned long long* m64 = (const unsigned long long*)mycA;
            unsigned long long raw[4] = {m64[0], m64[1], m64[2], m64[3]};
            unsigned long long C[16];
            #pragma unroll
            for (int i = 0; i < 16; ++i) {
                int m = (int)((raw[i >> 2] >> ((i & 3) * 16)) & 0x3FF);
                float u = uval(Zs[m], nA0, nA1, nA2);
                float d = fmaxf(fmaf(2.0f, u, xqA), 0.0f);
                unsigned long long key =
                    ((unsigned long long)__float_as_uint(d) << 32) | (unsigned)m;
                C[i] = (i < cntA) ? key : ~0ULL;
            }
            sort16(C);
            #pragma unroll
            for (int round = 1; round <= 2; round <<= 1) {
                unsigned long long o[16];
                #pragma unroll
                for (int i = 0; i < 16; ++i) o[i] = __shfl_xor(C[i], round, 64);
                #pragma unroll
                for (int i = 0; i < 16; ++i) {
                    unsigned long long b = o[15 - i];
                    C[i] = C[i] < b ? C[i] : b;
                }
                cleanup16(C);
            }
            if (sub == 0) {
                #pragma unroll
                for (int i = 0; i < 16; ++i) qb[pt * QSTRIDE + i] = C[i];
            }
        } else if (sub == 0) {
            unsigned long long R[16];
            #pragma unroll
            for (int i = 0; i < 16; ++i) R[i] = ~0ULL;
            for (int m = 0; m < M_IND; ++m) {
                float u = uval(Zs[m], nA0, nA1, nA2);
                float d = fmaxf(fmaf(2.0f, u, xqA), 0.0f);
                unsigned long long kk =
                    ((unsigned long long)__float_as_uint(d) << 32) | (unsigned)m;
                if (kk < R[15]) {
                    #pragma unroll
                    for (int j = 0; j < 16; ++j) {
                        unsigned long long t = R[j];
                        bool cc = kk < t;
                        R[j] = cc ? kk : t;
                        kk = cc ? t : kk;
                    }
                }
            }
            #pragma unroll
            for (int i = 0; i < 16; ++i) qb[pt * QSTRIDE + i] = R[i];
        }

        if (!ovfB) {
            const unsigned long long* m64 = (const unsigned long long*)mycB;
            unsigned long long raw[4] = {m64[0], m64[1], m64[2], m64[3]};
            unsigned long long C[16];
            #pragma unroll
            for (int i = 0; i < 16; ++i) {
                int m = (int)((raw[i >> 2] >> ((i & 3) * 16)) & 0x3FF);
                float u = uval(Zs[m], nB0, nB1, nB2);
                float d = fmaxf(fmaf(2.0f, u, xqB), 0.0f);
                unsigned long long key =
                    ((unsigned long long)__float_as_uint(d) << 32) | (unsigned)m;
                C[i] = (i < cntB) ? key : ~0ULL;
            }
            sort16(C);
            #pragma unroll
            for (int round = 1; round <= 2; round <<= 1) {
                unsigned long long o[16];
                #pragma unroll
                for (int i = 0; i < 16; ++i) o[i] = __shfl_xor(C[i], round, 64);
                #pragma unroll
                for (int i = 0; i < 16; ++i) {
                    unsigned long long b = o[15 - i];
                    C[i] = C[i] < b ? C[i] : b;
                }
                cleanup16(C);
            }
            if (sub == 0) {
                #pragma unroll
                for (int i = 0; i < 16; ++i) qb[(pt + 64) * QSTRIDE + i] = C[i];
            }
        } else if (sub == 0) {
            unsigned long long R[16];
            #pragma unroll
            for (int i = 0; i < 16; ++i) R[i] = ~0ULL;
            for (int m = 0; m < M_IND; ++m) {
                float u = uval(Zs[m], nB0, nB1, nB2);
                float d = fmaxf(fmaf(2.0f, u, xqB), 0.0f);
                unsigned long long kk =
                    ((unsigned long long)__float_as_uint(d) << 32) | (unsigned)m;
                if (kk < R[15]) {
                    #pragma unroll
                    for (int j = 0; j < 16; ++j) {
                        unsigned long long t = R[j];
                        bool cc = kk < t;
                        R[j] = cc ? kk : t;
                        kk = cc ? t : kk;
                    }
                }
            }
            #pragma unroll
            for (int i = 0; i < 16; ++i) qb[(pt + 64) * QSTRIDE + i] = R[i];
        }
    }
    __syncthreads();

    if (MODE == 2) {
        if (tid == 0) {
            while (__hip_atomic_load(ctr, __ATOMIC_ACQUIRE, __HIP_MEMORY_SCOPE_AGENT)
                   < (unsigned)GRID_BLKS)
                __builtin_amdgcn_s_sleep(8);
        }
        __syncthreads();
    }
    if (tid >= PTS_PER_BLK) return;

    int n = blockIdx.x * PTS_PER_BLK + tid;
    int idx[KNN];
    float kv[KNN];
    float nx[KNN], ny[KNN], nz[KNN], nq[KNN];
    #pragma unroll
    for (int a = 0; a < KNN; ++a) {
        unsigned long long k = qb[tid * QSTRIDE + a];
        idx[a] = (int)(k & 0xFFFFFFFFULL);
        float d = __uint_as_float((unsigned)(k >> 32));
        kv[a] = __expf(-0.5f * d);
        float4 z = Zs[idx[a]];
        nx[a] = z.x; ny[a] = z.y; nz[a] = z.z; nq[a] = z.w;
    }

    float A[KNN * (KNN + 1) / 2];
    #pragma unroll
    for (int r = 0; r < KNN; ++r) {
        A[r * (r + 1) / 2 + r] = 1.0f + 2.0f * JITTER;
        #pragma unroll
        for (int c = 0; c < r; ++c) {
            float dot = fmaf(nx[r], nx[c], fmaf(ny[r], ny[c], nz[r] * nz[c]));
            A[r * (r + 1) / 2 + c] = __expf(fminf(dot - nq[r] - nq[c], 0.0f));
        }
    }

    #pragma unroll
    for (int c = 0; c < KNN; ++c) {
        float diag = A[c * (c + 1) / 2 + c];
        #pragma unroll
        for (int k = 0; k < c; ++k) {
            float l = A[c * (c + 1) / 2 + k];
            diag = fmaf(-l, l, diag);
        }
        float rinv = __frsqrt_rn(fmaxf(diag, 1e-12f));
        A[c * (c + 1) / 2 + c] = rinv;
        #pragma unroll
        for (int r = c + 1; r < KNN; ++r) {
            float v = A[r * (r + 1) / 2 + c];
            #pragma unroll
            for (int k = 0; k < c; ++k)
                v = fmaf(-A[r * (r + 1) / 2 + k], A[c * (c + 1) / 2 + k], v);
            A[r * (r + 1) / 2 + c] = v * rinv;
        }
    }

    float w[KNN];
    #pragma unroll
    for (int r = 0; r < KNN; ++r) {
        float v = kv[r];
        #pragma unroll
        for (int c = 0; c < r; ++c) v = fmaf(-A[r * (r + 1) / 2 + c], w[c], v);
        w[r] = v * A[r * (r + 1) / 2 + r];
    }
    #pragma unroll
    for (int r = KNN - 1; r >= 0; --r) {
        float v = w[r];
        #pragma unroll
        for (int c = r + 1; c < KNN; ++c) v = fmaf(-A[c * (c + 1) / 2 + r], w[c], v);
        w[r] = v * A[r * (r + 1) / 2 + r];
    }

    float wk = 0.f, ww = 0.f, mean = 0.f;
    #pragma unroll
    for (int a = 0; a < KNN; ++a) {
        wk = fmaf(w[a], kv[a], wk);
        ww = fmaf(w[a], w[a], ww);
        mean = fmaf(w[a], mus[idx[a]], mean);
    }

    float qs = 0.f;
    if (MODE != 0) {
        #pragma unroll
        for (int r = 0; r < KNN; ++r) {
            int a = idx[r];
            float wr = w[r];
            float rowacc = 0.f;
            #pragma unroll
            for (int c = 0; c < r; ++c) {
                int b = idx[c];
                int hi = a > b ? a : b;
                int lo = a > b ? b : a;
                rowacc = fmaf(w[c], P[((unsigned)hi * (hi + 1) >> 1) + lo], rowacc);
            }
            qs = fmaf(wr, fmaf(wr, P[((unsigned)a * (a + 1) >> 1) + a], 2.0f * rowacc), qs);
        }
    } else {
        int si[KNN]; float sw[KNN];
        #pragma unroll
        for (int a = 0; a < KNN; ++a) { si[a] = idx[a]; sw[a] = w[a]; }
        #pragma unroll
        for (int a = 1; a < KNN; ++a) {
            int iv = si[a]; float wv = sw[a];
            int b = a - 1;
            while (b >= 0 && si[b] > iv) { si[b + 1] = si[b]; sw[b + 1] = sw[b]; --b; }
            si[b + 1] = iv; sw[b + 1] = wv;
        }
        int s = 0;
        int kend = si[KNN - 1];
        for (int k = 0; k <= kend; ++k) {
            float v = 0.f;
            if (s < KNN && si[s] == k) {
                v = sw[s] * __expf(Lu_raw[(unsigned)k * M_IND + k]);
                ++s;
            }
            for (int a = s; a < KNN; ++a)
                v = fmaf(sw[a], Lu_raw[(unsigned)si[a] * M_IND + k], v);
            qs = fmaf(v, v, qs);
        }
    }

    float cov = 1.0f - (wk - JITTER * ww) + qs;
    float sd = sqrtf(fmaxf(cov, 0.05f));
    out[n] = mean;
    out[N_PTS + n] = sd;
}

// ---------------------------------------------------------------------------
extern "C" void kernel_launch(void* const* d_in, const int* in_sizes, int n_in,
                              void* d_out, int out_size, void* d_ws, size_t ws_size,
                              hipStream_t stream) {
    const float* X      = (const float*)d_in[0];
    const float* Z      = (const float*)d_in[1];
    const float* Lu_raw = (const float*)d_in[2];
    const float* mu     = (const float*)d_in[3];
    float* out = (float*)d_out;

    if (ws_size >= PACKED_BYTES + QBG_BYTES) {
        // Split path: sel (su + selection -> qbg), then phase 2. Kernel
        // boundary is the sync; no counter, no memset, no co-residency need.
        float* P = (float*)d_ws;
        unsigned long long* qbg = (unsigned long long*)((char*)d_ws + PACKED_BYTES);
        sel_kernel<<<N_PTS / 64, 256, 0, stream>>>(X, Z, P, Lu_raw, qbg);
        p2_kernel<<<N_PTS / 64, 128, 0, stream>>>(Z, mu, P, qbg, out);
    } else if (ws_size >= PACKED_BYTES + 64) {
        float* P = (float*)d_ws;
        unsigned int* ctr = (unsigned int*)((char*)d_ws + PACKED_BYTES);
        hipMemsetAsync(ctr, 0, sizeof(unsigned int), stream);
        vnngp_kernel<2><<<GRID_BLKS, 256, 0, stream>>>(X, Z, mu, P, Lu_raw, ctr, out);
    } else if (ws_size >= PACKED_BYTES) {
        float* P = (float*)d_ws;
        su_kernel<<<SU_BLOCKS, 256, 0, stream>>>(Lu_raw, P);
        vnngp_kernel<1><<<GRID_BLKS, 256, 0, stream>>>(X, Z, mu, P, Lu_raw, nullptr, out);
    } else {
        vnngp_kernel<0><<<GRID_BLKS, 256, 0, stream>>>(X, Z, mu, nullptr, Lu_raw, nullptr, out);
    }
}

// Round 5
// 163.563 us; speedup vs baseline: 1.0629x; 1.0629x over previous
//
#include <hip/hip_runtime.h>
#include <math.h>

#define N_PTS 65536
#define M_IND 1024
#define KNN 16
#define JITTER 1e-4f

// Packed lower-triangular Su: P[i*(i+1)/2 + j], j <= i.
#define PACKED_FLOATS (M_IND * (M_IND + 1) / 2)               // 524800
#define PACKED_BYTES  ((size_t)PACKED_FLOATS * sizeof(float)) // 2,099,200 B

#define TSU 32
#define SU_BLOCKS 528          // 32*33/2 triangular tiles
#define PTS_PER_BLK 128        // 512 blocks, 2/CU resident
#define QSTRIDE 17             // u64 per point row (136 B)
#define GRID_BLKS (N_PTS / PTS_PER_BLK)   // 512

// R15 ledger:
//  - R14 split ablation: sel+su = 76.5us, p2 ~= 70-76us standalone. Phases
//    are EQUAL; fused (110.9) already overlaps ~40us of p2 under selection.
//  - R15: fused + ALL-WAVE phase 2 (2 threads/point, row-parity qs split,
//    LDS exchange through the dead qb region). Waves 2-3 were idle in the
//    phase-2 tail; now they halve the scattered-P latency chain.
//  - Register regime (R11/R12): phase-2 live set needs the (256,2)
//    512-unified budget. Do NOT raise min-waves. Watch WRITE_SIZE ~3 MB.

// ---------------------------------------------------------------------------
// One 32x32 Su tile (packed tril(Lu Lu^T)). As/Bs are LDS scratch.
// ---------------------------------------------------------------------------
__device__ __forceinline__ void su_tile(const float* __restrict__ Lu_raw,
                                        float* __restrict__ P,
                                        int bid, int tid,
                                        float (*As)[36], float (*Bs)[36]) {
    int rt = (int)((sqrtf(8.0f * (float)bid + 1.0f) - 1.0f) * 0.5f);
    while ((rt + 1) * (rt + 2) / 2 <= bid) ++rt;
    while (rt * (rt + 1) / 2 > bid) --rt;
    int ct = bid - rt * (rt + 1) / 2;   // ct <= rt
    int i0 = rt * TSU, j0 = ct * TSU;

    int tx = tid & 15, ty = tid >> 4;
    int sr = tid >> 3, sc = (tid & 7) << 2;
    float a00 = 0.f, a01 = 0.f, a10 = 0.f, a11 = 0.f;

    int nch = ct + 1;                      // k-chunks of 32 (k <= j0+31)
    int gi = i0 + sr, gj = j0 + sr;
    float4 pa = *(const float4*)(Lu_raw + (unsigned)gi * M_IND + sc);
    float4 pb = *(const float4*)(Lu_raw + (unsigned)gj * M_IND + sc);

    for (int c = 0; c < nch; ++c) {
        int gk = (c << 5) + sc;
        float aa[4] = {pa.x, pa.y, pa.z, pa.w};
        float bb[4] = {pb.x, pb.y, pb.z, pb.w};
        #pragma unroll
        for (int q = 0; q < 4; ++q) {
            int k = gk + q;
            aa[q] = (k < gi) ? aa[q] : ((k == gi) ? __expf(aa[q]) : 0.0f);
            bb[q] = (k < gj) ? bb[q] : ((k == gj) ? __expf(bb[q]) : 0.0f);
        }
        *(float4*)&As[sr][sc] = make_float4(aa[0], aa[1], aa[2], aa[3]);
        *(float4*)&Bs[sr][sc] = make_float4(bb[0], bb[1], bb[2], bb[3]);
        __syncthreads();
        if (c + 1 < nch) {
            int kn = ((c + 1) << 5) + sc;
            pa = *(const float4*)(Lu_raw + (unsigned)gi * M_IND + kn);
            pb = *(const float4*)(Lu_raw + (unsigned)gj * M_IND + kn);
        }
        #pragma unroll
        for (int kk = 0; kk < 32; kk += 4) {
            float4 av0 = *(const float4*)&As[ty][kk];
            float4 av1 = *(const float4*)&As[ty + 16][kk];
            float4 bv0 = *(const float4*)&Bs[tx][kk];
            float4 bv1 = *(const float4*)&Bs[tx + 16][kk];
            a00 = fmaf(av0.x, bv0.x, fmaf(av0.y, bv0.y, fmaf(av0.z, bv0.z, fmaf(av0.w, bv0.w, a00))));
            a01 = fmaf(av0.x, bv1.x, fmaf(av0.y, bv1.y, fmaf(av0.z, bv1.z, fmaf(av0.w, bv1.w, a01))));
            a10 = fmaf(av1.x, bv0.x, fmaf(av1.y, bv0.y, fmaf(av1.z, bv0.z, fmaf(av1.w, bv0.w, a10))));
            a11 = fmaf(av1.x, bv1.x, fmaf(av1.y, bv1.y, fmaf(av1.z, bv1.z, fmaf(av1.w, bv1.w, a11))));
        }
        __syncthreads();
    }

    int ia = i0 + ty, ib = i0 + ty + 16;
    int ja = j0 + tx, jb = j0 + tx + 16;
    if (ja <= ia) P[((unsigned)ia * (ia + 1) >> 1) + ja] = a00;
    if (jb <= ia) P[((unsigned)ia * (ia + 1) >> 1) + jb] = a01;
    if (ja <= ib) P[((unsigned)ib * (ib + 1) >> 1) + ja] = a10;
    if (jb <= ib) P[((unsigned)ib * (ib + 1) >> 1) + jb] = a11;
}

// Standalone su kernel (non-fused fallback path only).
__global__ __launch_bounds__(256) void su_kernel(const float* __restrict__ Lu_raw,
                                                 float* __restrict__ P) {
    __shared__ float As[TSU][36];
    __shared__ float Bs[TSU][36];
    su_tile(Lu_raw, P, blockIdx.x, threadIdx.x, As, Bs);
}

// ---------------------------------------------------------------------------
// Sorting-network helpers.
// ---------------------------------------------------------------------------
__device__ __forceinline__ void ce(unsigned long long& x, unsigned long long& y) {
    unsigned long long a = x, b = y;
    bool c = a < b;
    x = c ? a : b;
    y = c ? b : a;
}
__device__ __forceinline__ void ce(float& x, float& y) {
    float a = fminf(x, y), b = fmaxf(x, y);
    x = a; y = b;
}

template <typename KT>
__device__ __forceinline__ void sort16(KT* a) {
    #pragma unroll
    for (int p = 1; p < 16; p <<= 1)
        #pragma unroll
        for (int k = p; k >= 1; k >>= 1)
            #pragma unroll
            for (int j = k & (p - 1); j + k < 16; j += 2 * k)
                #pragma unroll
                for (int i = 0; i < k; ++i)
                    if (i + j + k < 16)
                        if (((i + j) / (2 * p)) == ((i + j + k) / (2 * p)))
                            ce(a[i + j], a[i + j + k]);
}

template <typename KT>
__device__ __forceinline__ void cleanup16(KT* a) {
    #pragma unroll
    for (int d = 8; d >= 1; d >>= 1)
        #pragma unroll
        for (int i = 0; i < 16; ++i)
            if ((i & d) == 0) ce(a[i], a[i | d]);
}

// u-space distance surrogate: u = 0.5*|z|^2 - x.z  (Zs.w holds 0.5*|z|^2).
// d = max(2u + xq, 0) is monotone in u.
__device__ __forceinline__ float uval(float4 z, float xn0, float xn1, float xn2) {
    return fmaf(xn0, z.x, fmaf(xn1, z.y, fmaf(xn2, z.z, z.w)));
}

// ---------------------------------------------------------------------------
// MODE 2: fused (su tiles in-kernel + device-flag sync). MODE 1: two-kernel.
// MODE 0: no-workspace exact fallback.
// 512 blocks x 256 thr, 128 pts/blk, selection: 2 pts/thread-quad;
// phase 2: 2 threads/point (row-parity qs split), ALL waves active.
// ---------------------------------------------------------------------------
template <int MODE>
__global__ __launch_bounds__(256, 2) void vnngp_kernel(const float* __restrict__ X,
                                                       const float* __restrict__ Z,
                                                       const float* __restrict__ mu,
                                                       float* __restrict__ P,
                                                       const float* __restrict__ Lu_raw,
                                                       unsigned int* __restrict__ ctr,
                                                       float* __restrict__ out) {
    __shared__ __align__(16) char smem[37888];
    float4* Zs = (float4*)smem;                                  // 16 KB
    float* mus = (float*)(smem + 16384);                         // 4 KB
    unsigned long long* qb = (unsigned long long*)(smem + 20480); // 17 KB
    int tid = threadIdx.x;

    for (int r = tid; r < M_IND; r += 256) {
        float zx = Z[r * 3 + 0], zy = Z[r * 3 + 1], zz = Z[r * 3 + 2];
        Zs[r] = make_float4(zx, zy, zz, 0.5f * (zx * zx + zy * zy + zz * zz));
        mus[r] = mu[r];
    }

    if (MODE == 2) {
        // In-kernel Su tiles (As/Bs alias the qb region: 9216 <= 17408 B).
        // Tile permutation: the 16 grid-stride "extra" tiles are the CHEAP
        // ct=0 single-chunk tiles (ids r(r+1)/2, r=16..31); the main
        // assignment skips them, so no block stacks a second expensive tile.
        float (*As)[36] = (float (*)[36])(smem + 20480);
        float (*Bs)[36] = (float (*)[36])(smem + 20480 + 4608);
        int t = blockIdx.x;
        #pragma unroll
        for (int r = 16; r < 32; ++r) {
            int s = (r * (r + 1)) >> 1;
            if (t >= s) ++t;
        }
        su_tile(Lu_raw, P, t, tid, As, Bs);       // contains __syncthreads
        if (blockIdx.x < 16) {
            int r = 16 + blockIdx.x;
            su_tile(Lu_raw, P, (r * (r + 1)) >> 1, tid, As, Bs);
        }
        __syncthreads();                           // P stores drained (vmcnt)
        if (tid == 0) {
            __threadfence();                       // device-scope release
            atomicAdd(ctr, 1u);
        }
    } else {
        __syncthreads();
    }

    {
        int pt = tid >> 2, sub = tid & 3;     // pt 0..63, quad handles pt & pt+64
        int nA = blockIdx.x * PTS_PER_BLK + pt;
        int nB = nA + 64;
        float xA0 = X[nA * 3 + 0], xA1 = X[nA * 3 + 1], xA2 = X[nA * 3 + 2];
        float xB0 = X[nB * 3 + 0], xB1 = X[nB * 3 + 1], xB2 = X[nB * 3 + 2];
        float xqA = fmaf(xA0, xA0, fmaf(xA1, xA1, xA2 * xA2));
        float xqB = fmaf(xB0, xB0, fmaf(xB1, xB1, xB2 * xB2));
        float nA0 = -xA0, nA1 = -xA1, nA2 = -xA2;
        float nB0 = -xB0, nB1 = -xB1, nB2 = -xB2;
        int mbase = sub << 8;
        int rot = sub << 1;   // subs land on disjoint bank quads

        // ---- Pass 1: 16 interleaved class minima per point (u-space) ----
        float TA[16], TB[16];
        #pragma unroll
        for (int j = 0; j < 16; ++j) { TA[j] = 3.4e38f; TB[j] = 3.4e38f; }
        #pragma unroll 1
        for (int c = 0; c < 16; ++c) {
            int base = mbase + (c << 4);
            #pragma unroll
            for (int j = 0; j < 16; ++j) {
                int m = base + ((j + rot) & 15);
                float4 z = Zs[m];
                TA[j] = fminf(TA[j], uval(z, nA0, nA1, nA2));
                TB[j] = fminf(TB[j], uval(z, nB0, nB1, nB2));
            }
        }
        sort16(TA);
        sort16(TB);
        #pragma unroll
        for (int round = 1; round <= 2; round <<= 1) {
            float oA[16], oB[16];
            #pragma unroll
            for (int i = 0; i < 16; ++i) {
                oA[i] = __shfl_xor(TA[i], round, 64);
                oB[i] = __shfl_xor(TB[i], round, 64);
            }
            #pragma unroll
            for (int i = 0; i < 16; ++i) {
                TA[i] = fminf(TA[i], oA[15 - i]);
                TB[i] = fminf(TB[i], oB[15 - i]);
            }
            cleanup16(TA);
            cleanup16(TB);
        }
        float TstarA = TA[15], TstarB = TB[15];   // u-space thresholds

        // ---- Pass 2: collect indices with u <= Tstar (u16, cap 16/sub) ----
        unsigned short* mycA = ((unsigned short*)qb) + pt * (QSTRIDE * 4) + sub * 16;
        unsigned short* mycB = ((unsigned short*)qb) + (pt + 64) * (QSTRIDE * 4) + sub * 16;
        int cntA = 0, cntB = 0;
        #pragma unroll 1
        for (int c = 0; c < 16; ++c) {
            int base = mbase + (c << 4);
            #pragma unroll
            for (int j = 0; j < 16; ++j) {
                int m = base + ((j + rot) & 15);
                float4 z = Zs[m];
                float uA = uval(z, nA0, nA1, nA2);
                float uB = uval(z, nB0, nB1, nB2);
                if (uA <= TstarA) { if (cntA < 16) mycA[cntA] = (unsigned short)m; ++cntA; }
                if (uB <= TstarB) { if (cntB < 16) mycB[cntB] = (unsigned short)m; ++cntB; }
            }
        }

        int ovfA = cntA > 16 ? 1 : 0;
        ovfA |= __shfl_xor(ovfA, 1, 64);
        ovfA |= __shfl_xor(ovfA, 2, 64);
        int ovfB = cntB > 16 ? 1 : 0;
        ovfB |= __shfl_xor(ovfB, 1, 64);
        ovfB |= __shfl_xor(ovfB, 2, 64);

        // ---- finalize point A ----
        if (!ovfA) {
            const unsigned long long* m64 = (const unsigned long long*)mycA;
            unsigned long long raw[4] = {m64[0], m64[1], m64[2], m64[3]};
            unsigned long long C[16];
            #pragma unroll
            for (int i = 0; i < 16; ++i) {
                int m = (int)((raw[i >> 2] >> ((i & 3) * 16)) & 0x3FF);
                float u = uval(Zs[m], nA0, nA1, nA2);
                float d = fmaxf(fmaf(2.0f, u, xqA), 0.0f);
                unsigned long long key =
                    ((unsigned long long)__float_as_uint(d) << 32) | (unsigned)m;
                C[i] = (i < cntA) ? key : ~0ULL;
            }
            sort16(C);
            #pragma unroll
            for (int round = 1; round <= 2; round <<= 1) {
                unsigned long long o[16];
                #pragma unroll
                for (int i = 0; i < 16; ++i) o[i] = __shfl_xor(C[i], round, 64);
                #pragma unroll
                for (int i = 0; i < 16; ++i) {
                    unsigned long long b = o[15 - i];
                    C[i] = C[i] < b ? C[i] : b;
                }
                cleanup16(C);
            }
            if (sub == 0) {
                #pragma unroll
                for (int i = 0; i < 16; ++i) qb[pt * QSTRIDE + i] = C[i];
            }
        } else if (sub == 0) {
            unsigned long long R[16];
            #pragma unroll
            for (int i = 0; i < 16; ++i) R[i] = ~0ULL;
            for (int m = 0; m < M_IND; ++m) {
                float u = uval(Zs[m], nA0, nA1, nA2);
                float d = fmaxf(fmaf(2.0f, u, xqA), 0.0f);
                unsigned long long kk =
                    ((unsigned long long)__float_as_uint(d) << 32) | (unsigned)m;
                if (kk < R[15]) {
                    #pragma unroll
                    for (int j = 0; j < 16; ++j) {
                        unsigned long long t = R[j];
                        bool cc = kk < t;
                        R[j] = cc ? kk : t;
                        kk = cc ? t : kk;
                    }
                }
            }
            #pragma unroll
            for (int i = 0; i < 16; ++i) qb[pt * QSTRIDE + i] = R[i];
        }

        // ---- finalize point B ----
        if (!ovfB) {
            const unsigned long long* m64 = (const unsigned long long*)mycB;
            unsigned long long raw[4] = {m64[0], m64[1], m64[2], m64[3]};
            unsigned long long C[16];
            #pragma unroll
            for (int i = 0; i < 16; ++i) {
                int m = (int)((raw[i >> 2] >> ((i & 3) * 16)) & 0x3FF);
                float u = uval(Zs[m], nB0, nB1, nB2);
                float d = fmaxf(fmaf(2.0f, u, xqB), 0.0f);
                unsigned long long key =
                    ((unsigned long long)__float_as_uint(d) << 32) | (unsigned)m;
                C[i] = (i < cntB) ? key : ~0ULL;
            }
            sort16(C);
            #pragma unroll
            for (int round = 1; round <= 2; round <<= 1) {
                unsigned long long o[16];
                #pragma unroll
                for (int i = 0; i < 16; ++i) o[i] = __shfl_xor(C[i], round, 64);
                #pragma unroll
                for (int i = 0; i < 16; ++i) {
                    unsigned long long b = o[15 - i];
                    C[i] = C[i] < b ? C[i] : b;
                }
                cleanup16(C);
            }
            if (sub == 0) {
                #pragma unroll
                for (int i = 0; i < 16; ++i) qb[(pt + 64) * QSTRIDE + i] = C[i];
            }
        } else if (sub == 0) {
            unsigned long long R[16];
            #pragma unroll
            for (int i = 0; i < 16; ++i) R[i] = ~0ULL;
            for (int m = 0; m < M_IND; ++m) {
                float u = uval(Zs[m], nB0, nB1, nB2);
                float d = fmaxf(fmaf(2.0f, u, xqB), 0.0f);
                unsigned long long kk =
                    ((unsigned long long)__float_as_uint(d) << 32) | (unsigned)m;
                if (kk < R[15]) {
                    #pragma unroll
                    for (int j = 0; j < 16; ++j) {
                        unsigned long long t = R[j];
                        bool cc = kk < t;
                        R[j] = cc ? kk : t;
                        kk = cc ? t : kk;
                    }
                }
            }
            #pragma unroll
            for (int i = 0; i < 16; ++i) qb[(pt + 64) * QSTRIDE + i] = R[i];
        }
    }
    __syncthreads();

    if (MODE == 2) {
        // Wait for all blocks' Su tiles (selection above overlapped them).
        if (tid == 0) {
            while (__hip_atomic_load(ctr, __ATOMIC_ACQUIRE, __HIP_MEMORY_SCOPE_AGENT)
                   < (unsigned)GRID_BLKS)
                __builtin_amdgcn_s_sleep(8);
        }
        __syncthreads();
    }

    // ---- Phase 2: local GP, TWO threads per point (role-parity qs split).
    // role 0 = waves 0-1 (pts 0..127), role 1 = waves 2-3 (same pts).
    int role = tid >> 7;
    int pt2 = tid & 127;
    int n = blockIdx.x * PTS_PER_BLK + pt2;
    int idx[KNN];
    float kv[KNN];
    float nx[KNN], ny[KNN], nz[KNN], nq[KNN];
    #pragma unroll
    for (int a = 0; a < KNN; ++a) {
        unsigned long long k = qb[pt2 * QSTRIDE + a];
        idx[a] = (int)(k & 0xFFFFFFFFULL);
        float d = __uint_as_float((unsigned)(k >> 32));
        kv[a] = __expf(-0.5f * d);            // lKxz entries
        float4 z = Zs[idx[a]];
        nx[a] = z.x; ny[a] = z.y; nz[a] = z.z; nq[a] = z.w;   // nq = 0.5*|z|^2
    }
    __syncthreads();   // qb reads drained before the xch overlay reuse below

    // A = lKzz + JITTER*I (lower tri); diag = 1 + 2*JITTER.
    // Off-diag: exp(-0.5*max(sq,0)) = exp(min(dot - nq[r] - nq[c], 0)).
    float A[KNN * (KNN + 1) / 2];
    #pragma unroll
    for (int r = 0; r < KNN; ++r) {
        A[r * (r + 1) / 2 + r] = 1.0f + 2.0f * JITTER;
        #pragma unroll
        for (int c = 0; c < r; ++c) {
            float dot = fmaf(nx[r], nx[c], fmaf(ny[r], ny[c], nz[r] * nz[c]));
            A[r * (r + 1) / 2 + c] = __expf(fminf(dot - nq[r] - nq[c], 0.0f));
        }
    }

    // In-place Cholesky; 1/L[c][c] stored on the diagonal (rsqrt).
    #pragma unroll
    for (int c = 0; c < KNN; ++c) {
        float diag = A[c * (c + 1) / 2 + c];
        #pragma unroll
        for (int k = 0; k < c; ++k) {
            float l = A[c * (c + 1) / 2 + k];
            diag = fmaf(-l, l, diag);
        }
        float rinv = __frsqrt_rn(fmaxf(diag, 1e-12f));
        A[c * (c + 1) / 2 + c] = rinv;
        #pragma unroll
        for (int r = c + 1; r < KNN; ++r) {
            float v = A[r * (r + 1) / 2 + c];
            #pragma unroll
            for (int k = 0; k < c; ++k)
                v = fmaf(-A[r * (r + 1) / 2 + k], A[c * (c + 1) / 2 + k], v);
            A[r * (r + 1) / 2 + c] = v * rinv;
        }
    }

    // Solve A w = kv (forward then backward).
    float w[KNN];
    #pragma unroll
    for (int r = 0; r < KNN; ++r) {
        float v = kv[r];
        #pragma unroll
        for (int c = 0; c < r; ++c) v = fmaf(-A[r * (r + 1) / 2 + c], w[c], v);
        w[r] = v * A[r * (r + 1) / 2 + r];
    }
    #pragma unroll
    for (int r = KNN - 1; r >= 0; --r) {
        float v = w[r];
        #pragma unroll
        for (int c = r + 1; c < KNN; ++c) v = fmaf(-A[c * (c + 1) / 2 + r], w[c], v);
        w[r] = v * A[r * (r + 1) / 2 + r];
    }

    // W lKzz W^T = w.k - JITTER*||w||^2   (A w = k, lKzz = A - JITTER*I)
    float wk = 0.f, ww = 0.f, mean = 0.f;
    #pragma unroll
    for (int a = 0; a < KNN; ++a) {
        wk = fmaf(w[a], kv[a], wk);
        ww = fmaf(w[a], w[a], ww);
        mean = fmaf(w[a], mus[idx[a]], mean);
    }

    // qs = w^T Su[idx,idx] w — rows split by parity across the role pair
    // (validated in R14's p2_kernel).
    float qs_p = 0.f;
    if (MODE != 0) {
        #pragma unroll
        for (int r = 0; r < KNN; ++r) {
            if ((r & 1) == role) {
                int a = idx[r];
                float wr = w[r];
                float rowacc = 0.f;
                #pragma unroll
                for (int c = 0; c < r; ++c) {
                    int b = idx[c];
                    int hi = a > b ? a : b;
                    int lo = a > b ? b : a;
                    rowacc = fmaf(w[c], P[((unsigned)hi * (hi + 1) >> 1) + lo], rowacc);
                }
                qs_p = fmaf(wr, fmaf(wr, P[((unsigned)a * (a + 1) >> 1) + a], 2.0f * rowacc), qs_p);
            }
        }
    } else if (role == 0) {
        // On-demand fallback (role 0 computes full qs; role 1 contributes 0).
        int si[KNN]; float sw[KNN];
        #pragma unroll
        for (int a = 0; a < KNN; ++a) { si[a] = idx[a]; sw[a] = w[a]; }
        #pragma unroll
        for (int a = 1; a < KNN; ++a) {
            int iv = si[a]; float wv = sw[a];
            int b = a - 1;
            while (b >= 0 && si[b] > iv) { si[b + 1] = si[b]; sw[b + 1] = sw[b]; --b; }
            si[b + 1] = iv; sw[b + 1] = wv;
        }
        int s = 0;
        int kend = si[KNN - 1];
        for (int k = 0; k <= kend; ++k) {
            float v = 0.f;
            if (s < KNN && si[s] == k) {
                v = sw[s] * __expf(Lu_raw[(unsigned)k * M_IND + k]);
                ++s;
            }
            for (int a = s; a < KNN; ++a)
                v = fmaf(sw[a], Lu_raw[(unsigned)si[a] * M_IND + k], v);
            qs_p = fmaf(v, v, qs_p);
        }
    }

    // Exchange role-1 partials through the (now dead) qb region.
    float* xch = (float*)qb;
    if (role == 1) xch[pt2] = qs_p;
    __syncthreads();
    if (role == 0) {
        float qs = qs_p + xch[pt2];
        float cov = 1.0f - (wk - JITTER * ww) + qs;
        float sd = sqrtf(fmaxf(cov, 0.05f));
        out[n] = mean;
        out[N_PTS + n] = sd;
    }
}

// ---------------------------------------------------------------------------
extern "C" void kernel_launch(void* const* d_in, const int* in_sizes, int n_in,
                              void* d_out, int out_size, void* d_ws, size_t ws_size,
                              hipStream_t stream) {
    const float* X      = (const float*)d_in[0];
    const float* Z      = (const float*)d_in[1];
    const float* Lu_raw = (const float*)d_in[2];
    const float* mu     = (const float*)d_in[3];
    float* out = (float*)d_out;

    if (ws_size >= PACKED_BYTES + 64) {
        // Fused: P + completion counter live in d_ws.
        float* P = (float*)d_ws;
        unsigned int* ctr = (unsigned int*)((char*)d_ws + PACKED_BYTES);
        hipMemsetAsync(ctr, 0, sizeof(unsigned int), stream);
        vnngp_kernel<2><<<GRID_BLKS, 256, 0, stream>>>(X, Z, mu, P, Lu_raw, ctr, out);
    } else if (ws_size >= PACKED_BYTES) {
        float* P = (float*)d_ws;
        su_kernel<<<SU_BLOCKS, 256, 0, stream>>>(Lu_raw, P);
        vnngp_kernel<1><<<GRID_BLKS, 256, 0, stream>>>(X, Z, mu, P, Lu_raw, nullptr, out);
    } else {
        vnngp_kernel<0><<<GRID_BLKS, 256, 0, stream>>>(X, Z, mu, nullptr, Lu_raw, nullptr, out);
    }
}